// Round 1
// baseline (377.378 us; speedup 1.0000x reference)
//
#include <hip/hip_runtime.h>
#include <stdint.h>

#define D_MODEL 1024
#define NHEAD   16
#define DK      64
#define BATCH   4
#define SEQ     2048
#define MTOT    (BATCH*SEQ)   // 8192

typedef __attribute__((ext_vector_type(4))) float  f32x4;
typedef __attribute__((ext_vector_type(8))) __bf16 bf16x8;
typedef __attribute__((ext_vector_type(8))) unsigned short u16x8;

__device__ __forceinline__ unsigned short f2bf(float f) {
    unsigned u = __builtin_bit_cast(unsigned, f);
    u += 0x7fffu + ((u >> 16) & 1u);
    return (unsigned short)(u >> 16);
}

// ---------------- convert x (fp32 -> bf16) ----------------
__global__ __launch_bounds__(256) void cvt_x_kernel(const float* __restrict__ x,
                                                    unsigned short* __restrict__ xb) {
    size_t i = ((size_t)blockIdx.x * 256 + threadIdx.x) * 8;
    f32x4 a = *(const f32x4*)(x + i);
    f32x4 b = *(const f32x4*)(x + i + 4);
    u16x8 o;
    o[0] = f2bf(a[0]); o[1] = f2bf(a[1]); o[2] = f2bf(a[2]); o[3] = f2bf(a[3]);
    o[4] = f2bf(b[0]); o[5] = f2bf(b[1]); o[6] = f2bf(b[2]); o[7] = f2bf(b[3]);
    *(u16x8*)(xb + i) = o;
}

// ------------- transpose+convert W[k][n] -> W^T[n][k] bf16 -------------
__global__ __launch_bounds__(256) void cvt_wt_kernel(const float* __restrict__ Wq,
                                                     const float* __restrict__ Wk,
                                                     const float* __restrict__ Wv,
                                                     unsigned short* __restrict__ wt) {
    __shared__ float tile[32][33];
    int mat = blockIdx.z;
    const float* W = (mat == 0) ? Wq : (mat == 1) ? Wk : Wv;
    int n0 = blockIdx.x * 32;
    int k0 = blockIdx.y * 32;
    int tx = threadIdx.x;       // 0..31
    int ty = threadIdx.y;       // 0..7
    #pragma unroll
    for (int i = 0; i < 4; ++i)
        tile[ty + i*8][tx] = W[(size_t)(k0 + ty + i*8) * D_MODEL + n0 + tx];
    __syncthreads();
    unsigned short* dst = wt + (size_t)mat * D_MODEL * D_MODEL;
    #pragma unroll
    for (int i = 0; i < 4; ++i)
        dst[(size_t)(n0 + ty + i*8) * D_MODEL + k0 + tx] = f2bf(tile[tx][ty + i*8]);
}

// ---------------- QKV projection GEMM ----------------
// C[m][n] = x[m][:] . W^T[n][:]  + bias[n],  Q scaled by 0.125, stored bf16
// into qkv[mat][b][h][s][dk].
#define BM 128
#define BN 128
#define BKK 64
__global__ __launch_bounds__(256) void qkv_gemm_kernel(const unsigned short* __restrict__ xb,
                                                       const unsigned short* __restrict__ wt,
                                                       const float* __restrict__ bq,
                                                       const float* __restrict__ bk,
                                                       const float* __restrict__ bv,
                                                       unsigned short* __restrict__ qkv) {
    __shared__ __align__(16) unsigned char sA[BM * BKK * 2];
    __shared__ __align__(16) unsigned char sB[BN * BKK * 2];

    int nb   = blockIdx.x;            // 0..23
    int mb   = blockIdx.y;            // 0..63
    int mat  = nb >> 3;
    int col0 = (nb & 7) * BN;
    int m0   = mb * BM;
    int t    = threadIdx.x;
    int lane = t & 63;
    int w    = t >> 6;

    const unsigned short* wmat = wt + (size_t)mat * D_MODEL * D_MODEL;
    const float* bias = (mat == 0) ? bq : (mat == 1) ? bk : bv;

    f32x4 acc[4][4];
    #pragma unroll
    for (int i = 0; i < 4; ++i)
        #pragma unroll
        for (int j = 0; j < 4; ++j)
            acc[i][j] = (f32x4)0.0f;

    int rA = (w >> 1) * 64;
    int rB = (w & 1) * 64;

    for (int ks = 0; ks < D_MODEL / BKK; ++ks) {
        int K0 = ks * BKK;
        // stage A and B tiles: 1024 16B-chunks each, 256 threads x 4
        #pragma unroll
        for (int i = 0; i < 4; ++i) {
            int c   = t + 256 * i;
            int row = c >> 3;
            int kc  = c & 7;
            int swz = kc ^ (row & 7);
            const unsigned short* ga = xb + (size_t)(m0 + row) * D_MODEL + K0 + swz * 8;
            __builtin_amdgcn_global_load_lds(
                (const __attribute__((address_space(1))) void*)ga,
                (__attribute__((address_space(3))) void*)(sA + c * 16), 16, 0, 0);
            const unsigned short* gb = wmat + (size_t)(col0 + row) * D_MODEL + K0 + swz * 8;
            __builtin_amdgcn_global_load_lds(
                (const __attribute__((address_space(1))) void*)gb,
                (__attribute__((address_space(3))) void*)(sB + c * 16), 16, 0, 0);
        }
        __syncthreads();

        #pragma unroll
        for (int kk = 0; kk < 2; ++kk) {
            bf16x8 af[4], bf[4];
            int kc = kk * 4 + (lane >> 4);
            #pragma unroll
            for (int mt = 0; mt < 4; ++mt) {
                int row = rA + mt * 16 + (lane & 15);
                int swz = kc ^ (row & 7);
                af[mt] = *(const bf16x8*)(sA + row * 128 + swz * 16);
            }
            #pragma unroll
            for (int nt = 0; nt < 4; ++nt) {
                int row = rB + nt * 16 + (lane & 15);
                int swz = kc ^ (row & 7);
                bf[nt] = *(const bf16x8*)(sB + row * 128 + swz * 16);
            }
            #pragma unroll
            for (int mt = 0; mt < 4; ++mt)
                #pragma unroll
                for (int nt = 0; nt < 4; ++nt)
                    acc[mt][nt] = __builtin_amdgcn_mfma_f32_16x16x32_bf16(
                        af[mt], bf[nt], acc[mt][nt], 0, 0, 0);
        }
        __syncthreads();
    }

    // epilogue: bias, scale (Q only), head-split store as bf16
    #pragma unroll
    for (int mt = 0; mt < 4; ++mt) {
        #pragma unroll
        for (int nt = 0; nt < 4; ++nt) {
            int gn = col0 + rB + nt * 16 + (lane & 15);
            float bval = bias[gn];
            #pragma unroll
            for (int r = 0; r < 4; ++r) {
                int gm = m0 + rA + mt * 16 + (lane >> 4) * 4 + r;
                float v = acc[mt][nt][r] + bval;
                if (mat == 0) v *= 0.125f;   // fold 1/sqrt(dk) into Q
                int b = gm >> 11, s = gm & 2047;
                int h = gn >> 6,  d = gn & 63;
                qkv[(size_t)mat * MTOT * D_MODEL +
                    ((size_t)(b * NHEAD + h) * SEQ + s) * DK + d] = f2bf(v);
            }
        }
    }
}

// ---------------- fused flash attention ----------------
// grid: (64 bh, 16 q-blocks), 256 threads = 4 waves, each wave 32 q-rows.
#define KVB 64
#define LDK 72      // padded row length (bf16 elems) -> 144B stride
__global__ __launch_bounds__(256) void attn_kernel(const unsigned short* __restrict__ qkv,
                                                   float* __restrict__ out) {
    __shared__ __align__(16) unsigned char sK[KVB * LDK * 2];        // K[kv][feat]
    __shared__ __align__(16) unsigned char sV[DK * LDK * 2];         // V^T[d][kv]
    __shared__ __align__(16) unsigned char sP[4][32 * LDK * 2];      // per-wave P

    int bh   = blockIdx.x;    // 0..63  (b*16+h)
    int qb   = blockIdx.y;    // 0..15
    int t    = threadIdx.x;
    int lane = t & 63;
    int w    = t >> 6;

    const unsigned short* Qb = qkv + (size_t)bh * SEQ * DK;
    const unsigned short* Kb = qkv + (size_t)MTOT * D_MODEL + (size_t)bh * SEQ * DK;
    const unsigned short* Vb = qkv + (size_t)2 * MTOT * D_MODEL + (size_t)bh * SEQ * DK;

    int q0 = qb * 128 + w * 32;

    // Q fragments in registers (already scaled by 1/8)
    bf16x8 aq[2][2];
    #pragma unroll
    for (int mt = 0; mt < 2; ++mt)
        #pragma unroll
        for (int kk = 0; kk < 2; ++kk)
            aq[mt][kk] = *(const bf16x8*)(Qb + (size_t)(q0 + mt * 16 + (lane & 15)) * DK
                                          + kk * 32 + (lane >> 4) * 8);

    f32x4 o[2][4];
    float mrun[2][4], lrun[2][4];
    #pragma unroll
    for (int mt = 0; mt < 2; ++mt)
        #pragma unroll
        for (int i = 0; i < 4; ++i) {
            o[mt][i] = (f32x4)0.0f;
            mrun[mt][i] = -1e30f;
            lrun[mt][i] = 0.0f;
        }

    for (int kt = 0; kt < SEQ / KVB; ++kt) {
        int kv0 = kt * KVB;
        // ---- stage K tile [64][64] -> sK padded ----
        #pragma unroll
        for (int i = 0; i < 2; ++i) {
            int c = t + 256 * i;
            int row = c >> 3, kc = c & 7;
            u16x8 v = *(const u16x8*)(Kb + (size_t)(kv0 + row) * DK + kc * 8);
            *(u16x8*)(sK + row * (LDK * 2) + kc * 16) = v;
        }
        // ---- stage V tile transposed -> sV[d][kv] ----
        #pragma unroll
        for (int i = 0; i < 2; ++i) {
            int c = t + 256 * i;
            int row = c >> 3, d0 = (c & 7) * 8;
            u16x8 v = *(const u16x8*)(Vb + (size_t)(kv0 + row) * DK + d0);
            #pragma unroll
            for (int j = 0; j < 8; ++j)
                *(unsigned short*)(sV + (d0 + j) * (LDK * 2) + row * 2) = v[j];
        }
        __syncthreads();

        // ---- S = Q K^T (per wave: 32 x 64) ----
        f32x4 sc[2][4];
        #pragma unroll
        for (int mt = 0; mt < 2; ++mt)
            #pragma unroll
            for (int nt = 0; nt < 4; ++nt)
                sc[mt][nt] = (f32x4)0.0f;
        #pragma unroll
        for (int kk = 0; kk < 2; ++kk) {
            bf16x8 bk[4];
            #pragma unroll
            for (int nt = 0; nt < 4; ++nt)
                bk[nt] = *(const bf16x8*)(sK + (nt * 16 + (lane & 15)) * (LDK * 2)
                                          + kk * 64 + (lane >> 4) * 16);
            #pragma unroll
            for (int mt = 0; mt < 2; ++mt)
                #pragma unroll
                for (int nt = 0; nt < 4; ++nt)
                    sc[mt][nt] = __builtin_amdgcn_mfma_f32_16x16x32_bf16(
                        aq[mt][kk], bk[nt], sc[mt][nt], 0, 0, 0);
        }

        // ---- online softmax (rows live in 16-lane groups) ----
        #pragma unroll
        for (int mt = 0; mt < 2; ++mt) {
            #pragma unroll
            for (int r = 0; r < 4; ++r) {
                float mx = fmaxf(fmaxf(sc[mt][0][r], sc[mt][1][r]),
                                 fmaxf(sc[mt][2][r], sc[mt][3][r]));
                #pragma unroll
                for (int off = 8; off; off >>= 1)
                    mx = fmaxf(mx, __shfl_xor(mx, off, 16));
                float mold = mrun[mt][r];
                float mnew = fmaxf(mold, mx);
                float alpha = __expf(mold - mnew);
                float rs = 0.0f;
                #pragma unroll
                for (int nt = 0; nt < 4; ++nt) {
                    float p = __expf(sc[mt][nt][r] - mnew);
                    sc[mt][nt][r] = p;
                    rs += p;
                }
                #pragma unroll
                for (int off = 8; off; off >>= 1)
                    rs += __shfl_xor(rs, off, 16);
                mrun[mt][r] = mnew;
                lrun[mt][r] = lrun[mt][r] * alpha + rs;
                #pragma unroll
                for (int dt = 0; dt < 4; ++dt)
                    o[mt][dt][r] *= alpha;
            }
        }

        // ---- write P (bf16) to per-wave LDS for A-frag re-layout ----
        #pragma unroll
        for (int mt = 0; mt < 2; ++mt)
            #pragma unroll
            for (int nt = 0; nt < 4; ++nt)
                #pragma unroll
                for (int r = 0; r < 4; ++r) {
                    int row = mt * 16 + (lane >> 4) * 4 + r;
                    int col = nt * 16 + (lane & 15);
                    *(unsigned short*)(sP[w] + row * (LDK * 2) + col * 2)
                        = f2bf(sc[mt][nt][r]);
                }

        // ---- O += P V ----
        #pragma unroll
        for (int kk = 0; kk < 2; ++kk) {
            bf16x8 pa[2], bv[4];
            #pragma unroll
            for (int mt = 0; mt < 2; ++mt)
                pa[mt] = *(const bf16x8*)(sP[w] + (mt * 16 + (lane & 15)) * (LDK * 2)
                                          + kk * 64 + (lane >> 4) * 16);
            #pragma unroll
            for (int dt = 0; dt < 4; ++dt)
                bv[dt] = *(const bf16x8*)(sV + (dt * 16 + (lane & 15)) * (LDK * 2)
                                          + kk * 64 + (lane >> 4) * 16);
            #pragma unroll
            for (int mt = 0; mt < 2; ++mt)
                #pragma unroll
                for (int dt = 0; dt < 4; ++dt)
                    o[mt][dt] = __builtin_amdgcn_mfma_f32_16x16x32_bf16(
                        pa[mt], bv[dt], o[mt][dt], 0, 0, 0);
        }
        __syncthreads();
    }

    // ---- normalize + write out[b][s][h*64+d] fp32 ----
    int b = bh >> 4, h = bh & 15;
    #pragma unroll
    for (int mt = 0; mt < 2; ++mt) {
        #pragma unroll
        for (int r = 0; r < 4; ++r) {
            int q = q0 + mt * 16 + (lane >> 4) * 4 + r;
            float rl = 1.0f / lrun[mt][r];
            #pragma unroll
            for (int dt = 0; dt < 4; ++dt)
                out[((size_t)b * SEQ + q) * D_MODEL + h * DK + dt * 16 + (lane & 15)]
                    = o[mt][dt][r] * rl;
        }
    }
}

extern "C" void kernel_launch(void* const* d_in, const int* in_sizes, int n_in,
                              void* d_out, int out_size, void* d_ws, size_t ws_size,
                              hipStream_t stream) {
    const float* x  = (const float*)d_in[0];
    const float* Wq = (const float*)d_in[1];
    const float* bq = (const float*)d_in[2];
    const float* Wk = (const float*)d_in[3];
    const float* bk = (const float*)d_in[4];
    const float* Wv = (const float*)d_in[5];
    const float* bv = (const float*)d_in[6];
    float* out = (float*)d_out;

    unsigned short* xb  = (unsigned short*)d_ws;                       // 16 MB
    unsigned short* wt  = xb + (size_t)MTOT * D_MODEL;                 // 6 MB
    unsigned short* qkv = wt + (size_t)3 * D_MODEL * D_MODEL;          // 48 MB

    cvt_x_kernel<<<dim3(MTOT * D_MODEL / (256 * 8)), dim3(256), 0, stream>>>(x, xb);
    cvt_wt_kernel<<<dim3(32, 32, 3), dim3(32, 8), 0, stream>>>(Wq, Wk, Wv, wt);
    qkv_gemm_kernel<<<dim3(24, 64), dim3(256), 0, stream>>>(xb, wt, bq, bk, bv, qkv);
    attn_kernel<<<dim3(64, 16), dim3(256), 0, stream>>>(qkv, out);
}

// Round 4
// 350.306 us; speedup vs baseline: 1.0773x; 1.0773x over previous
//
#include <hip/hip_runtime.h>
#include <stdint.h>

#define D_MODEL 1024
#define NHEAD   16
#define DK      64
#define BATCH   4
#define SEQ     2048
#define MTOT    (BATCH*SEQ)   // 8192
#define KVB     64
#define NT      (SEQ/KVB)     // 32

typedef __attribute__((ext_vector_type(4)))  float  f32x4;
typedef __attribute__((ext_vector_type(16))) float  f32x16;
typedef __attribute__((ext_vector_type(8)))  __bf16 bf16x8;
typedef __attribute__((ext_vector_type(8)))  unsigned short u16x8;
typedef __attribute__((ext_vector_type(4)))  unsigned int u32x4;

__device__ __forceinline__ unsigned short f2bf(float f) {
    unsigned u = __builtin_bit_cast(unsigned, f);
    u += 0x7fffu + ((u >> 16) & 1u);
    return (unsigned short)(u >> 16);
}

// ---------------- convert x (fp32 -> bf16) ----------------
__global__ __launch_bounds__(256) void cvt_x_kernel(const float* __restrict__ x,
                                                    unsigned short* __restrict__ xb) {
    size_t i = ((size_t)blockIdx.x * 256 + threadIdx.x) * 8;
    f32x4 a = *(const f32x4*)(x + i);
    f32x4 b = *(const f32x4*)(x + i + 4);
    u16x8 o;
    o[0] = f2bf(a[0]); o[1] = f2bf(a[1]); o[2] = f2bf(a[2]); o[3] = f2bf(a[3]);
    o[4] = f2bf(b[0]); o[5] = f2bf(b[1]); o[6] = f2bf(b[2]); o[7] = f2bf(b[3]);
    *(u16x8*)(xb + i) = o;
}

// ------------- transpose+convert W[k][n] -> W^T[n][k] bf16 -------------
__global__ __launch_bounds__(256) void cvt_wt_kernel(const float* __restrict__ Wq,
                                                     const float* __restrict__ Wk,
                                                     const float* __restrict__ Wv,
                                                     unsigned short* __restrict__ wt) {
    __shared__ float tile[32][33];
    int mat = blockIdx.z;
    const float* W = (mat == 0) ? Wq : (mat == 1) ? Wk : Wv;
    int n0 = blockIdx.x * 32;
    int k0 = blockIdx.y * 32;
    int tx = threadIdx.x;       // 0..31
    int ty = threadIdx.y;       // 0..7
    #pragma unroll
    for (int i = 0; i < 4; ++i)
        tile[ty + i*8][tx] = W[(size_t)(k0 + ty + i*8) * D_MODEL + n0 + tx];
    __syncthreads();
    unsigned short* dst = wt + (size_t)mat * D_MODEL * D_MODEL;
    #pragma unroll
    for (int i = 0; i < 4; ++i)
        dst[(size_t)(n0 + ty + i*8) * D_MODEL + k0 + tx] = f2bf(tile[tx][ty + i*8]);
}

// ---------------- QKV projection GEMM ----------------
// Q,K stored as [b][h][s][dk]; V stored TRANSPOSED as [b][h][dk][s] so the
// attention kernel can read V^T fragments (contiguous kv) straight from global.
#define BM 128
#define BN 128
#define BKK 64
__global__ __launch_bounds__(256) void qkv_gemm_kernel(const unsigned short* __restrict__ xb,
                                                       const unsigned short* __restrict__ wt,
                                                       const float* __restrict__ bq,
                                                       const float* __restrict__ bk,
                                                       const float* __restrict__ bv,
                                                       unsigned short* __restrict__ qkv) {
    __shared__ __align__(16) unsigned char sA[BM * BKK * 2];
    __shared__ __align__(16) unsigned char sB[BN * BKK * 2];

    int nb   = blockIdx.x;            // 0..23
    int mb   = blockIdx.y;            // 0..63
    int mat  = nb >> 3;
    int col0 = (nb & 7) * BN;
    int m0   = mb * BM;
    int t    = threadIdx.x;
    int lane = t & 63;
    int w    = t >> 6;

    const unsigned short* wmat = wt + (size_t)mat * D_MODEL * D_MODEL;
    const float* bias = (mat == 0) ? bq : (mat == 1) ? bk : bv;

    f32x4 acc[4][4];
    #pragma unroll
    for (int i = 0; i < 4; ++i)
        #pragma unroll
        for (int j = 0; j < 4; ++j)
            acc[i][j] = (f32x4)0.0f;

    int rA = (w >> 1) * 64;
    int rB = (w & 1) * 64;

    for (int ks = 0; ks < D_MODEL / BKK; ++ks) {
        int K0 = ks * BKK;
        #pragma unroll
        for (int i = 0; i < 4; ++i) {
            int c   = t + 256 * i;
            int row = c >> 3;
            int kc  = c & 7;
            int swz = kc ^ (row & 7);
            const unsigned short* ga = xb + (size_t)(m0 + row) * D_MODEL + K0 + swz * 8;
            __builtin_amdgcn_global_load_lds(
                (const __attribute__((address_space(1))) void*)ga,
                (__attribute__((address_space(3))) void*)(sA + c * 16), 16, 0, 0);
            const unsigned short* gb = wmat + (size_t)(col0 + row) * D_MODEL + K0 + swz * 8;
            __builtin_amdgcn_global_load_lds(
                (const __attribute__((address_space(1))) void*)gb,
                (__attribute__((address_space(3))) void*)(sB + c * 16), 16, 0, 0);
        }
        __syncthreads();

        #pragma unroll
        for (int kk = 0; kk < 2; ++kk) {
            bf16x8 af[4], bf[4];
            int kc = kk * 4 + (lane >> 4);
            #pragma unroll
            for (int mt = 0; mt < 4; ++mt) {
                int row = rA + mt * 16 + (lane & 15);
                int swz = kc ^ (row & 7);
                af[mt] = *(const bf16x8*)(sA + row * 128 + swz * 16);
            }
            #pragma unroll
            for (int nt = 0; nt < 4; ++nt) {
                int row = rB + nt * 16 + (lane & 15);
                int swz = kc ^ (row & 7);
                bf[nt] = *(const bf16x8*)(sB + row * 128 + swz * 16);
            }
            #pragma unroll
            for (int mt = 0; mt < 4; ++mt)
                #pragma unroll
                for (int nt = 0; nt < 4; ++nt)
                    acc[mt][nt] = __builtin_amdgcn_mfma_f32_16x16x32_bf16(
                        af[mt], bf[nt], acc[mt][nt], 0, 0, 0);
        }
        __syncthreads();
    }

    #pragma unroll
    for (int mt = 0; mt < 4; ++mt) {
        #pragma unroll
        for (int nt = 0; nt < 4; ++nt) {
            int gn = col0 + rB + nt * 16 + (lane & 15);
            float bval = bias[gn];
            #pragma unroll
            for (int r = 0; r < 4; ++r) {
                int gm = m0 + rA + mt * 16 + (lane >> 4) * 4 + r;
                float v = acc[mt][nt][r] + bval;
                if (mat == 0) v *= 0.125f;   // fold 1/sqrt(dk) into Q
                int b = gm >> 11, s = gm & 2047;
                int h = gn >> 6,  d = gn & 63;
                size_t idx;
                if (mat == 2)   // V transposed: [b][h][d][s]
                    idx = ((size_t)(b * NHEAD + h) * DK + d) * SEQ + s;
                else            // Q,K: [b][h][s][d]
                    idx = ((size_t)(b * NHEAD + h) * SEQ + s) * DK + d;
                qkv[(size_t)mat * MTOT * D_MODEL + idx] = f2bf(v);
            }
        }
    }
}

// ---------------- fused flash attention (swapped-QK^T, 32x32 MFMA, no LDS) ----------------
// grid: (64 bh, 16 q-blocks of 128), 256 threads = 4 waves, each wave 32 q-rows.
// All K / V^T fragment loads come straight from global (L1/L2-resident per bh;
// all 16 q-blocks of one bh map to the same XCD since blockid%8 == bh%8).
#define CVTPK(dst, lo_, hi_) \
    asm("v_cvt_pk_bf16_f32 %0, %1, %2" : "=v"(dst) : "v"(lo_), "v"(hi_))

// Build a P^T B-fragment (col=q, k=hi*8+j) from 8 per-lane P values whose
// C-layout kv rows are {r0..r3}@(hi=0) / {r0..r3}+4@(hi=1) and {r4..r7} likewise.
__device__ __forceinline__ bf16x8 make_pf(float p0, float p1, float p2, float p3,
                                          float p4, float p5, float p6, float p7,
                                          int hi) {
    unsigned a1, a2, b1, b2;
    CVTPK(a1, p0, p1); CVTPK(a2, p2, p3);
    CVTPK(b1, p4, p5); CVTPK(b2, p6, p7);
    unsigned sa1 = (unsigned)__shfl_xor((int)a1, 32);
    unsigned sa2 = (unsigned)__shfl_xor((int)a2, 32);
    unsigned sb1 = (unsigned)__shfl_xor((int)b1, 32);
    unsigned sb2 = (unsigned)__shfl_xor((int)b2, 32);
    u32x4 u = { hi ? sb1 : a1,     // k 0,1 : kv base+{0,1}(hi0) / +{8,9}(hi1 from partner)
                hi ? sb2 : a2,     // k 2,3
                hi ? b1  : sa1,    // k 4,5 : kv base+{4,5}(hi0 from partner) / +{12,13}(hi1)
                hi ? b2  : sa2 };  // k 6,7
    return __builtin_bit_cast(bf16x8, u);
}

__global__ __launch_bounds__(256) void attn_kernel(const unsigned short* __restrict__ qkv,
                                                   float* __restrict__ out) {
    int bh = blockIdx.x;      // b*16 + h
    int qb = blockIdx.y;      // 0..15
    int lane = threadIdx.x & 63;
    int w = threadIdx.x >> 6;
    int hi = lane >> 5;       // 0/1
    int l31 = lane & 31;

    const unsigned short* Qb = qkv + (size_t)bh * SEQ * DK;
    const unsigned short* Kb = qkv + (size_t)MTOT * D_MODEL + (size_t)bh * SEQ * DK;
    const unsigned short* Vt = qkv + (size_t)2 * MTOT * D_MODEL + (size_t)bh * DK * SEQ; // [d][s]

    int qbase = qb * 128 + w * 32;

    // Q B-frags: col=q=lane&31, k=d=kd*16+hi*8+j   (Q pre-scaled by 1/8)
    bf16x8 aq[4];
    #pragma unroll
    for (int kd = 0; kd < 4; ++kd)
        aq[kd] = *(const bf16x8*)(Qb + (size_t)(qbase + l31) * DK + kd * 16 + hi * 8);

    f32x16 o0 = (f32x16)0.0f, o1 = (f32x16)0.0f;   // O^T[d][q], d-halves 0/1
    float mrun = -3e38f, lrun = 0.0f;

    for (int kt = 0; kt < NT; ++kt) {
        int kv0 = kt * KVB;

        // ---- K A-frags: row=kv=lane&31(+32), k=d=kd*16+hi*8+j ----
        bf16x8 ak0[4], ak1[4];
        #pragma unroll
        for (int kd = 0; kd < 4; ++kd)
            ak0[kd] = *(const bf16x8*)(Kb + (size_t)(kv0 + l31) * DK + kd * 16 + hi * 8);
        #pragma unroll
        for (int kd = 0; kd < 4; ++kd)
            ak1[kd] = *(const bf16x8*)(Kb + (size_t)(kv0 + 32 + l31) * DK + kd * 16 + hi * 8);
        // ---- V^T A-frags (issue early; consumed after softmax): row=d, k=kv ----
        bf16x8 av0[4], av1[4];
        #pragma unroll
        for (int ks = 0; ks < 4; ++ks)
            av0[ks] = *(const bf16x8*)(Vt + (size_t)l31 * SEQ + kv0 + ks * 16 + hi * 8);
        #pragma unroll
        for (int ks = 0; ks < 4; ++ks)
            av1[ks] = *(const bf16x8*)(Vt + (size_t)(32 + l31) * SEQ + kv0 + ks * 16 + hi * 8);

        // ---- S^T = K Q^T ----
        f32x16 sc0 = (f32x16)0.0f, sc1 = (f32x16)0.0f;
        #pragma unroll
        for (int kd = 0; kd < 4; ++kd) {
            sc0 = __builtin_amdgcn_mfma_f32_32x32x16_bf16(ak0[kd], aq[kd], sc0, 0, 0, 0);
            sc1 = __builtin_amdgcn_mfma_f32_32x32x16_bf16(ak1[kd], aq[kd], sc1, 0, 0, 0);
        }

        // ---- online softmax: lane owns q-column; kv rows split across hi ----
        float mx = sc0[0];
        #pragma unroll
        for (int i = 1; i < 16; ++i) mx = fmaxf(mx, sc0[i]);
        #pragma unroll
        for (int i = 0; i < 16; ++i) mx = fmaxf(mx, sc1[i]);
        mx = fmaxf(mx, __shfl_xor(mx, 32));
        float mnew = fmaxf(mrun, mx);
        float alpha = __expf(mrun - mnew);
        float rs = 0.0f;
        #pragma unroll
        for (int i = 0; i < 16; ++i) { float p = __expf(sc0[i] - mnew); sc0[i] = p; rs += p; }
        #pragma unroll
        for (int i = 0; i < 16; ++i) { float p = __expf(sc1[i] - mnew); sc1[i] = p; rs += p; }
        rs += __shfl_xor(rs, 32);
        mrun = mnew;
        lrun = lrun * alpha + rs;
        #pragma unroll
        for (int i = 0; i < 16; ++i) { o0[i] *= alpha; o1[i] *= alpha; }

        // ---- P^T -> bf16 B-frags (shfl-based half exchange) ----
        bf16x8 pf0 = make_pf(sc0[0], sc0[1], sc0[2],  sc0[3],  sc0[4],  sc0[5],  sc0[6],  sc0[7],  hi);
        bf16x8 pf1 = make_pf(sc0[8], sc0[9], sc0[10], sc0[11], sc0[12], sc0[13], sc0[14], sc0[15], hi);
        bf16x8 pf2 = make_pf(sc1[0], sc1[1], sc1[2],  sc1[3],  sc1[4],  sc1[5],  sc1[6],  sc1[7],  hi);
        bf16x8 pf3 = make_pf(sc1[8], sc1[9], sc1[10], sc1[11], sc1[12], sc1[13], sc1[14], sc1[15], hi);

        // ---- O^T += V^T P^T ----
        o0 = __builtin_amdgcn_mfma_f32_32x32x16_bf16(av0[0], pf0, o0, 0, 0, 0);
        o1 = __builtin_amdgcn_mfma_f32_32x32x16_bf16(av1[0], pf0, o1, 0, 0, 0);
        o0 = __builtin_amdgcn_mfma_f32_32x32x16_bf16(av0[1], pf1, o0, 0, 0, 0);
        o1 = __builtin_amdgcn_mfma_f32_32x32x16_bf16(av1[1], pf1, o1, 0, 0, 0);
        o0 = __builtin_amdgcn_mfma_f32_32x32x16_bf16(av0[2], pf2, o0, 0, 0, 0);
        o1 = __builtin_amdgcn_mfma_f32_32x32x16_bf16(av1[2], pf2, o1, 0, 0, 0);
        o0 = __builtin_amdgcn_mfma_f32_32x32x16_bf16(av0[3], pf3, o0, 0, 0, 0);
        o1 = __builtin_amdgcn_mfma_f32_32x32x16_bf16(av1[3], pf3, o1, 0, 0, 0);
    }

    // ---- epilogue: direct f32x4 stores (C rows are 4-contiguous in d) ----
    int b = bh >> 4, h = bh & 15;
    float rl = 1.0f / lrun;
    float* dst = out + ((size_t)b * SEQ + qbase + l31) * D_MODEL + h * DK;
    #pragma unroll
    for (int g = 0; g < 4; ++g) {
        int d0 = 8 * g + 4 * hi;
        f32x4 v0 = { o0[4*g] * rl, o0[4*g+1] * rl, o0[4*g+2] * rl, o0[4*g+3] * rl };
        *(f32x4*)(dst + d0) = v0;
        f32x4 v1 = { o1[4*g] * rl, o1[4*g+1] * rl, o1[4*g+2] * rl, o1[4*g+3] * rl };
        *(f32x4*)(dst + 32 + d0) = v1;
    }
}

extern "C" void kernel_launch(void* const* d_in, const int* in_sizes, int n_in,
                              void* d_out, int out_size, void* d_ws, size_t ws_size,
                              hipStream_t stream) {
    const float* x  = (const float*)d_in[0];
    const float* Wq = (const float*)d_in[1];
    const float* bq = (const float*)d_in[2];
    const float* Wk = (const float*)d_in[3];
    const float* bk = (const float*)d_in[4];
    const float* Wv = (const float*)d_in[5];
    const float* bv = (const float*)d_in[6];
    float* out = (float*)d_out;

    unsigned short* xb  = (unsigned short*)d_ws;                       // 16 MB
    unsigned short* wt  = xb + (size_t)MTOT * D_MODEL;                 // 6 MB
    unsigned short* qkv = wt + (size_t)3 * D_MODEL * D_MODEL;          // 48 MB

    cvt_x_kernel<<<dim3(MTOT * D_MODEL / (256 * 8)), dim3(256), 0, stream>>>(x, xb);
    cvt_wt_kernel<<<dim3(32, 32, 3), dim3(32, 8), 0, stream>>>(Wq, Wk, Wv, wt);
    qkv_gemm_kernel<<<dim3(24, 64), dim3(256), 0, stream>>>(xb, wt, bq, bk, bv, qkv);
    attn_kernel<<<dim3(64, 16), dim3(256), 0, stream>>>(qkv, out);
}